// Round 3
// baseline (216.579 us; speedup 1.0000x reference)
//
#include <hip/hip_runtime.h>

// SSIM loss, fused. Input: enhanced, target fp32 [16,3,512,512]. Output: scalar fp32.
// V4: register-resident sliding window. 1 block = 1 wave = 256 cols (float4/lane)
// x 16 output rows. Horizontal 7-tap via shfl (+2 edge-lane halo loads), vertical
// 7-tap from a 7-row x 5-channel register ring with static %7 slots (unrolled
// 7-phase blocks). No LDS, no barriers, 2 coalesced float4 loads per row.

#define IMG_H 512
#define IMG_W 512
#define NPLANES 48               // 16 * 3
#define CHUNK 16                 // output rows per wave
#define SSIM_C1 1.0e-4f
#define SSIM_C2 9.0e-4f

static __device__ constexpr float G[7] = {
    0.03663284536f, 0.11128076166f, 0.21674531251f, 0.27068216094f,
    0.21674531251f, 0.11128076166f, 0.03663284536f};

// One phase: consume image row GY into ring slot P; if DO_OUT, emit output row GY-3.
// All ring indices are compile-time constants (P, (P+1+k)%7).
#define SSIM_PHASE(P, GY, DO_OUT) do {                                          \
    constexpr int p_ = (P);                                                     \
    const int gy_ = (GY);                                                       \
    float4 xv = make_float4(0.f, 0.f, 0.f, 0.f);                                \
    float4 yv = make_float4(0.f, 0.f, 0.f, 0.f);                                \
    float4 hlx = make_float4(0.f, 0.f, 0.f, 0.f);                               \
    float4 hly = make_float4(0.f, 0.f, 0.f, 0.f);                               \
    float4 hrx = make_float4(0.f, 0.f, 0.f, 0.f);                               \
    float4 hry = make_float4(0.f, 0.f, 0.f, 0.f);                               \
    if ((unsigned)gy_ < (unsigned)IMG_H) {                                      \
      const float* xr_ = xp + (size_t)gy_ * IMG_W;                              \
      const float* yr_ = yp + (size_t)gy_ * IMG_W;                              \
      xv = *reinterpret_cast<const float4*>(xr_ + c0);                          \
      yv = *reinterpret_cast<const float4*>(yr_ + c0);                          \
      if (needL) { hlx = *reinterpret_cast<const float4*>(xr_ + 252);           \
                   hly = *reinterpret_cast<const float4*>(yr_ + 252); }         \
      if (needR) { hrx = *reinterpret_cast<const float4*>(xr_ + 256);           \
                   hry = *reinterpret_cast<const float4*>(yr_ + 256); }         \
    }                                                                           \
    /* window cols c0-3..c0+6: own 4 + 3 left (lane-1) + 3 right (lane+1) */    \
    const float ax0 = l0 ? hlx.y : __shfl_up(xv.y, 1, 64);                      \
    const float ax1 = l0 ? hlx.z : __shfl_up(xv.z, 1, 64);                      \
    const float ax2 = l0 ? hlx.w : __shfl_up(xv.w, 1, 64);                      \
    const float ay0 = l0 ? hly.y : __shfl_up(yv.y, 1, 64);                      \
    const float ay1 = l0 ? hly.z : __shfl_up(yv.z, 1, 64);                      \
    const float ay2 = l0 ? hly.w : __shfl_up(yv.w, 1, 64);                      \
    const float bx0 = l63 ? hrx.x : __shfl_down(xv.x, 1, 64);                   \
    const float bx1 = l63 ? hrx.y : __shfl_down(xv.y, 1, 64);                   \
    const float bx2 = l63 ? hrx.z : __shfl_down(xv.z, 1, 64);                   \
    const float by0 = l63 ? hry.x : __shfl_down(yv.x, 1, 64);                   \
    const float by1 = l63 ? hry.y : __shfl_down(yv.y, 1, 64);                   \
    const float by2 = l63 ? hry.z : __shfl_down(yv.z, 1, 64);                   \
    const float wxc[10] = {ax0, ax1, ax2, xv.x, xv.y, xv.z, xv.w, bx0, bx1, bx2}; \
    const float wyc[10] = {ay0, ay1, ay2, yv.x, yv.y, yv.z, yv.w, by0, by1, by2}; \
    float s1_[4] = {0.f, 0.f, 0.f, 0.f};                                        \
    float s2_[4] = {0.f, 0.f, 0.f, 0.f};                                        \
    float sxx_[4] = {0.f, 0.f, 0.f, 0.f};                                       \
    float syy_[4] = {0.f, 0.f, 0.f, 0.f};                                       \
    float sxy_[4] = {0.f, 0.f, 0.f, 0.f};                                       \
    _Pragma("unroll")                                                           \
    for (int w_ = 0; w_ < 10; ++w_) {                                           \
      const float xw_ = wxc[w_], yw_ = wyc[w_];                                 \
      const float pxx_ = xw_ * xw_;                                             \
      const float pyy_ = yw_ * yw_;                                             \
      const float pxy_ = xw_ * yw_;                                             \
      _Pragma("unroll")                                                         \
      for (int j_ = 0; j_ < 4; ++j_) {                                          \
        const int k_ = w_ - j_; /* tap index for output col c0+j */             \
        if (k_ >= 0 && k_ < 7) {                                                \
          const float gk_ = G[k_];                                              \
          s1_[j_] = fmaf(gk_, xw_, s1_[j_]);                                    \
          s2_[j_] = fmaf(gk_, yw_, s2_[j_]);                                    \
          sxx_[j_] = fmaf(gk_, pxx_, sxx_[j_]);                                 \
          syy_[j_] = fmaf(gk_, pyy_, syy_[j_]);                                 \
          sxy_[j_] = fmaf(gk_, pxy_, sxy_[j_]);                                 \
        }                                                                       \
      }                                                                         \
    }                                                                           \
    _Pragma("unroll")                                                           \
    for (int j_ = 0; j_ < 4; ++j_) {                                            \
      W1[p_][j_] = s1_[j_];  W2[p_][j_] = s2_[j_];                              \
      WXX[p_][j_] = sxx_[j_]; WYY[p_][j_] = syy_[j_]; WXY[p_][j_] = sxy_[j_];   \
    }                                                                           \
    if (DO_OUT) {                                                               \
      float m1_[4] = {0.f, 0.f, 0.f, 0.f};                                      \
      float m2_[4] = {0.f, 0.f, 0.f, 0.f};                                      \
      float exx_[4] = {0.f, 0.f, 0.f, 0.f};                                     \
      float eyy_[4] = {0.f, 0.f, 0.f, 0.f};                                     \
      float exy_[4] = {0.f, 0.f, 0.f, 0.f};                                     \
      _Pragma("unroll")                                                         \
      for (int k_ = 0; k_ < 7; ++k_) {                                          \
        const int q_ = (p_ + 1 + k_) % 7; /* static ring slot */                \
        const float gk_ = G[k_];                                                \
        _Pragma("unroll")                                                       \
        for (int j_ = 0; j_ < 4; ++j_) {                                        \
          m1_[j_] = fmaf(gk_, W1[q_][j_], m1_[j_]);                             \
          m2_[j_] = fmaf(gk_, W2[q_][j_], m2_[j_]);                             \
          exx_[j_] = fmaf(gk_, WXX[q_][j_], exx_[j_]);                          \
          eyy_[j_] = fmaf(gk_, WYY[q_][j_], eyy_[j_]);                          \
          exy_[j_] = fmaf(gk_, WXY[q_][j_], exy_[j_]);                          \
        }                                                                       \
      }                                                                         \
      _Pragma("unroll")                                                         \
      for (int j_ = 0; j_ < 4; ++j_) {                                          \
        const float mu1sq_ = m1_[j_] * m1_[j_];                                 \
        const float mu2sq_ = m2_[j_] * m2_[j_];                                 \
        const float mu12_ = m1_[j_] * m2_[j_];                                  \
        const float v1_ = exx_[j_] - mu1sq_;                                    \
        const float v2_ = eyy_[j_] - mu2sq_;                                    \
        const float v12_ = exy_[j_] - mu12_;                                    \
        const float num_ = (2.f * mu12_ + SSIM_C1) * (2.f * v12_ + SSIM_C2);    \
        const float den_ = (mu1sq_ + mu2sq_ + SSIM_C1) * (v1_ + v2_ + SSIM_C2); \
        float r_ = __builtin_amdgcn_rcpf(den_);                                 \
        r_ = r_ * fmaf(-den_, r_, 2.f);                                         \
        accsum = fmaf(num_, r_, accsum);                                        \
      }                                                                         \
    }                                                                           \
  } while (0)

__global__ __launch_bounds__(64, 2) void ssim_slide_kernel(
    const float* __restrict__ x, const float* __restrict__ y,
    float* __restrict__ partial) {
  const int lane = threadIdx.x;           // 64 lanes = 256 cols (float4 each)
  const int strip = blockIdx.x;           // 0: cols 0-255, 1: cols 256-511
  const int chunk = blockIdx.y;           // 32 chunks of 16 output rows
  const int plane = blockIdx.z;

  const float* __restrict__ xp = x + (size_t)plane * (IMG_H * IMG_W);
  const float* __restrict__ yp = y + (size_t)plane * (IMG_H * IMG_W);
  const int c0 = strip * 256 + lane * 4;  // own cols c0..c0+3 (aligned float4)
  const int r0 = chunk * CHUNK;
  const int gy0 = r0 - 3;                 // first input row of the window

  const bool l0 = (lane == 0);
  const bool l63 = (lane == 63);
  const bool needL = l0 && (strip == 1);  // cross-strip halo cols 252-255
  const bool needR = l63 && (strip == 0); // cross-strip halo cols 256-259

  // 7-row ring of the 5 horizontally-filtered channels (registers only).
  float W1[7][4], W2[7][4], WXX[7][4], WYY[7][4], WXY[7][4];
  float accsum = 0.f;

  // Prologue: fill ring (rows gy0..gy0+5), first output at phase 6.
  SSIM_PHASE(0, gy0 + 0, 0);
  SSIM_PHASE(1, gy0 + 1, 0);
  SSIM_PHASE(2, gy0 + 2, 0);
  SSIM_PHASE(3, gy0 + 3, 0);
  SSIM_PHASE(4, gy0 + 4, 0);
  SSIM_PHASE(5, gy0 + 5, 0);
  SSIM_PHASE(6, gy0 + 6, 1);
  // Main: 2 blocks of 7 phases (rows gy0+7 .. gy0+20), slot = phase index.
  for (int b = 0; b < 2; ++b) {
    const int gb = gy0 + 7 + 7 * b;
    SSIM_PHASE(0, gb + 0, 1);
    SSIM_PHASE(1, gb + 1, 1);
    SSIM_PHASE(2, gb + 2, 1);
    SSIM_PHASE(3, gb + 3, 1);
    SSIM_PHASE(4, gb + 4, 1);
    SSIM_PHASE(5, gb + 5, 1);
    SSIM_PHASE(6, gb + 6, 1);
  }
  // Epilogue: row gy0+21 -> output row r0+15.
  SSIM_PHASE(0, gy0 + 21, 1);

  // Wave reduction; single wave per block, lane 0 writes the partial.
#pragma unroll
  for (int off = 32; off > 0; off >>= 1) accsum += __shfl_down(accsum, off, 64);
  if (lane == 0) {
    partial[(size_t)plane * 64 + (size_t)chunk * 2 + strip] = accsum;
  }
}

__global__ __launch_bounds__(256) void ssim_reduce_kernel(
    const float* __restrict__ partial, int n, float* __restrict__ out) {
  float acc = 0.f;
  const int nv = n >> 2;  // n = 3072 -> 768 float4
  const float4* __restrict__ p4 = reinterpret_cast<const float4*>(partial);
  for (int i = threadIdx.x; i < nv; i += 256) {
    const float4 v = p4[i];
    acc += (v.x + v.y) + (v.z + v.w);
  }
#pragma unroll
  for (int off = 32; off > 0; off >>= 1) acc += __shfl_down(acc, off, 64);
  __shared__ float wsum[4];
  if ((threadIdx.x & 63) == 0) wsum[threadIdx.x >> 6] = acc;
  __syncthreads();
  if (threadIdx.x == 0) {
    const float s = wsum[0] + wsum[1] + wsum[2] + wsum[3];
    out[0] = 1.f - s * (1.f / (float)(NPLANES * IMG_H * IMG_W));
  }
}

extern "C" void kernel_launch(void* const* d_in, const int* in_sizes, int n_in,
                              void* d_out, int out_size, void* d_ws, size_t ws_size,
                              hipStream_t stream) {
  const float* enhanced = (const float*)d_in[0];
  const float* target = (const float*)d_in[1];
  float* out = (float*)d_out;
  float* partial = (float*)d_ws;

  dim3 grid(2, IMG_H / CHUNK, NPLANES);   // 2 x 32 x 48 = 3072 single-wave blocks
  dim3 block(64, 1, 1);
  ssim_slide_kernel<<<grid, block, 0, stream>>>(enhanced, target, partial);

  const int nblocks = 2 * (IMG_H / CHUNK) * NPLANES;  // 3072
  ssim_reduce_kernel<<<1, 256, 0, stream>>>(partial, nblocks, out);
}

// Round 4
// 215.886 us; speedup vs baseline: 1.0032x; 1.0032x over previous
//
#include <hip/hip_runtime.h>

// SSIM loss, fused. Input: enhanced, target fp32 [16,3,512,512]. Output: scalar fp32.
// V5: persistent blocks (512 = 2/CU), double-buffered LDS, register prefetch of
// the next tile's inputs overlapped with the current tile's vertical pass, and
// raw s_barrier + lgkmcnt(0) (no vmcnt drain) so prefetch loads stay in flight
// across the barrier. Per-tile math identical to V3 (verified: absmax 0,
// bank conflicts 0).

#define TILE_W 64
#define TILE_H 16
#define HALO 3
#define IN_H 22                        // TILE_H + 2*HALO
#define H_STRIDE 68                    // 64 + 4: 16B-aligned, rotates banks by 4/row
#define CH_STRIDE (IN_H * H_STRIDE)    // 1496 floats per channel
#define LDSF (5 * CH_STRIDE)           // 7480 floats = 29,920 B per buffer
#define IMG_H 512
#define IMG_W 512
#define NPLANES 48                     // 16 * 3
#define NBLOCKS 512                    // 2 per CU (LDS-capped)
#define TPB 24                         // tiles per block: 12288 / 512
#define SSIM_C1 1.0e-4f
#define SSIM_C2 9.0e-4f

static __device__ constexpr float G[7] = {
    0.03663284536f, 0.11128076166f, 0.21674531251f, 0.27068216094f,
    0.21674531251f, 0.11128076166f, 0.03663284536f};

struct Win {  // 12-float window per image: cols [bcol, bcol+11]
  float4 xa, xb, xc, ya, yb, yc;
};

// Aligned float4 load with zero fill outside [0, IMG_W). col multiple of 4.
__device__ __forceinline__ float4 ld4z(const float* __restrict__ row, int col) {
  if (col >= 0 && col + 3 < IMG_W) {
    return *reinterpret_cast<const float4*>(row + col);
  }
  float4 v;
  v.x = ((unsigned)(col + 0) < IMG_W) ? row[col + 0] : 0.f;
  v.y = ((unsigned)(col + 1) < IMG_W) ? row[col + 1] : 0.f;
  v.z = ((unsigned)(col + 2) < IMG_W) ? row[col + 2] : 0.f;
  v.w = ((unsigned)(col + 3) < IMG_W) ? row[col + 3] : 0.f;
  return v;
}

__device__ __forceinline__ Win load_item(const float* __restrict__ xp,
                                         const float* __restrict__ yp,
                                         int gy, int bcol, bool edge) {
  Win w;
  if (!edge) {
    // Interior tiles: gy in [13,498], bcol in [60,444] -- all in-bounds.
    const float* xr = xp + (size_t)gy * IMG_W + bcol;
    const float* yr = yp + (size_t)gy * IMG_W + bcol;
    w.xa = *reinterpret_cast<const float4*>(xr);
    w.xb = *reinterpret_cast<const float4*>(xr + 4);
    w.xc = *reinterpret_cast<const float4*>(xr + 8);
    w.ya = *reinterpret_cast<const float4*>(yr);
    w.yb = *reinterpret_cast<const float4*>(yr + 4);
    w.yc = *reinterpret_cast<const float4*>(yr + 8);
  } else if ((unsigned)gy < (unsigned)IMG_H) {
    const float* xr = xp + (size_t)gy * IMG_W;
    const float* yr = yp + (size_t)gy * IMG_W;
    w.xa = ld4z(xr, bcol);     w.xb = ld4z(xr, bcol + 4);
    w.xc = ld4z(xr, bcol + 8);
    w.ya = ld4z(yr, bcol);     w.yb = ld4z(yr, bcol + 4);
    w.yc = ld4z(yr, bcol + 8);
  } else {
    const float4 z = make_float4(0.f, 0.f, 0.f, 0.f);
    w.xa = w.xb = w.xc = z;
    w.ya = w.yb = w.yc = z;
  }
  return w;
}

// Issue the global loads for one tile's inputs into registers.
__device__ __forceinline__ void load_tile(const float* __restrict__ x,
                                          const float* __restrict__ y, int t,
                                          int i0r, int i0c, bool has2, int i1r,
                                          int i1c, Win& w0, Win& w1) {
  const int plane = t >> 8;        // 256 tiles per plane
  const int rem = t & 255;
  const int ty = rem >> 3;         // 32 tile-rows
  const int tx = rem & 7;          // 8 tile-cols
  const float* xp = x + (size_t)plane * (IMG_H * IMG_W);
  const float* yp = y + (size_t)plane * (IMG_H * IMG_W);
  const int y0 = ty * TILE_H - HALO;
  const int cbase = tx * TILE_W - 4;
  const bool edge = (tx == 0) | (tx == 7) | (ty == 0) | (ty == 31);
  w0 = load_item(xp, yp, y0 + i0r, cbase + 4 * i0c, edge);
  if (has2) w1 = load_item(xp, yp, y0 + i1r, cbase + 4 * i1c, edge);
}

// Horizontal 7-tap over 5 channels for one (row, 4-col) item; write to LDS buf.
__device__ __forceinline__ void hpass_item(const Win& w, float* __restrict__ buf,
                                           int hr, int cg) {
  const float xin[12] = {w.xa.x, w.xa.y, w.xa.z, w.xa.w, w.xb.x, w.xb.y,
                         w.xb.z, w.xb.w, w.xc.x, w.xc.y, w.xc.z, w.xc.w};
  const float yin[12] = {w.ya.x, w.ya.y, w.ya.z, w.ya.w, w.yb.x, w.yb.y,
                         w.yb.z, w.yb.w, w.yc.x, w.yc.y, w.yc.z, w.yc.w};
  float a1[4] = {0.f, 0.f, 0.f, 0.f};
  float a2[4] = {0.f, 0.f, 0.f, 0.f};
  float axx[4] = {0.f, 0.f, 0.f, 0.f};
  float ayy[4] = {0.f, 0.f, 0.f, 0.f};
  float axy[4] = {0.f, 0.f, 0.f, 0.f};
#pragma unroll
  for (int wi = 1; wi < 12; ++wi) {
    const float xv = xin[wi];
    const float yv = yin[wi];
    const float pxx = xv * xv;
    const float pyy = yv * yv;
    const float pxy = xv * yv;
#pragma unroll
    for (int j = 0; j < 4; ++j) {
      const int k = wi - 1 - j;  // tap index for output col j
      if (k >= 0 && k < 7) {
        const float gk = G[k];
        a1[j] = fmaf(gk, xv, a1[j]);
        a2[j] = fmaf(gk, yv, a2[j]);
        axx[j] = fmaf(gk, pxx, axx[j]);
        ayy[j] = fmaf(gk, pyy, ayy[j]);
        axy[j] = fmaf(gk, pxy, axy[j]);
      }
    }
  }
  float* hb = buf + hr * H_STRIDE + 4 * cg;
  *reinterpret_cast<float4*>(hb + 0 * CH_STRIDE) =
      make_float4(a1[0], a1[1], a1[2], a1[3]);
  *reinterpret_cast<float4*>(hb + 1 * CH_STRIDE) =
      make_float4(a2[0], a2[1], a2[2], a2[3]);
  *reinterpret_cast<float4*>(hb + 2 * CH_STRIDE) =
      make_float4(axx[0], axx[1], axx[2], axx[3]);
  *reinterpret_cast<float4*>(hb + 3 * CH_STRIDE) =
      make_float4(ayy[0], ayy[1], ayy[2], ayy[3]);
  *reinterpret_cast<float4*>(hb + 4 * CH_STRIDE) =
      make_float4(axy[0], axy[1], axy[2], axy[3]);
}

// Vertical 7-tap + SSIM map for this thread's (column, 4 rows); returns px sum.
// Lane index = column -> bank (c + const) % 32: 2-way aliasing = free.
__device__ __forceinline__ float vpass(const float* __restrict__ buf, int tid) {
  const int c = tid & 63;
  const int r0 = (tid >> 6) * 4;
  const float* hb = buf + r0 * H_STRIDE + c;
  float m1[4] = {0.f, 0.f, 0.f, 0.f};
  float m2[4] = {0.f, 0.f, 0.f, 0.f};
  float exx[4] = {0.f, 0.f, 0.f, 0.f};
  float eyy[4] = {0.f, 0.f, 0.f, 0.f};
  float exy[4] = {0.f, 0.f, 0.f, 0.f};
#pragma unroll
  for (int j = 0; j < 10; ++j) {  // input rows r0+j, immediate offsets
    const float v1 = hb[0 * CH_STRIDE + j * H_STRIDE];
    const float v2 = hb[1 * CH_STRIDE + j * H_STRIDE];
    const float vxx = hb[2 * CH_STRIDE + j * H_STRIDE];
    const float vyy = hb[3 * CH_STRIDE + j * H_STRIDE];
    const float vxy = hb[4 * CH_STRIDE + j * H_STRIDE];
#pragma unroll
    for (int t = 0; t < 4; ++t) {
      const int k = j - t;  // tap index for output row r0+t
      if (k >= 0 && k < 7) {
        const float gk = G[k];
        m1[t] = fmaf(gk, v1, m1[t]);
        m2[t] = fmaf(gk, v2, m2[t]);
        exx[t] = fmaf(gk, vxx, exx[t]);
        eyy[t] = fmaf(gk, vyy, eyy[t]);
        exy[t] = fmaf(gk, vxy, exy[t]);
      }
    }
  }
  float acc = 0.f;
#pragma unroll
  for (int t = 0; t < 4; ++t) {
    const float mu1sq = m1[t] * m1[t];
    const float mu2sq = m2[t] * m2[t];
    const float mu12 = m1[t] * m2[t];
    const float s1 = exx[t] - mu1sq;
    const float s2 = eyy[t] - mu2sq;
    const float s12 = exy[t] - mu12;
    const float num = (2.f * mu12 + SSIM_C1) * (2.f * s12 + SSIM_C2);
    const float den = (mu1sq + mu2sq + SSIM_C1) * (s1 + s2 + SSIM_C2);
    float r = __builtin_amdgcn_rcpf(den);  // den > 0 always
    r = r * fmaf(-den, r, 2.f);            // 1 Newton step, ~1 ulp
    acc = fmaf(num, r, acc);
  }
  return acc;
}

// Barrier that keeps prefetch global loads in flight: wait LDS ops only.
__device__ __forceinline__ void lds_barrier() {
  __builtin_amdgcn_sched_barrier(0);
  asm volatile("s_waitcnt lgkmcnt(0)" ::: "memory");
  __builtin_amdgcn_s_barrier();
  __builtin_amdgcn_sched_barrier(0);
}

__global__ __launch_bounds__(256, 2) void ssim_pipe_kernel(
    const float* __restrict__ x, const float* __restrict__ y,
    float* __restrict__ partial) {
  __shared__ __align__(16) float hbuf0[LDSF];
  __shared__ __align__(16) float hbuf1[LDSF];
  __shared__ float wsum[4];

  const int tid = threadIdx.x;
  // h-pass item decode: item i = (row i>>4, colgroup i&15); 352 items, thread
  // tid owns item tid and (if tid<96) item 256+tid.
  const int i0r = tid >> 4, i0c = tid & 15;
  const bool has2 = tid < (IN_H * 16 - 256);  // 96
  const int i1r = (256 + tid) >> 4, i1c = (256 + tid) & 15;
  const int t0 = blockIdx.x * TPB;

  float accsum = 0.f;
  Win A0, A1, B0, B1;
  load_tile(x, y, t0, i0r, i0c, has2, i1r, i1c, A0, A1);

  for (int j = 0; j < TPB; j += 2) {
    // ---- tile t0+j ----
    hpass_item(A0, hbuf0, i0r, i0c);
    if (has2) hpass_item(A1, hbuf0, i1r, i1c);
    load_tile(x, y, t0 + j + 1, i0r, i0c, has2, i1r, i1c, B0, B1);  // prefetch
    lds_barrier();                 // h-writes visible; prefetch stays in flight
    accsum += vpass(hbuf0, tid);

    // ---- tile t0+j+1 ----
    hpass_item(B0, hbuf1, i0r, i0c);
    if (has2) hpass_item(B1, hbuf1, i1r, i1c);
    if (j + 2 < TPB) {
      load_tile(x, y, t0 + j + 2, i0r, i0c, has2, i1r, i1c, A0, A1);
    }
    lds_barrier();
    accsum += vpass(hbuf1, tid);
  }

  // Block reduction once per block (24 tiles accumulated per thread).
#pragma unroll
  for (int off = 32; off > 0; off >>= 1) accsum += __shfl_down(accsum, off, 64);
  if ((tid & 63) == 0) wsum[tid >> 6] = accsum;
  __syncthreads();
  if (tid == 0) {
    partial[blockIdx.x] = wsum[0] + wsum[1] + wsum[2] + wsum[3];
  }
}

__global__ __launch_bounds__(256) void ssim_reduce_kernel(
    const float* __restrict__ partial, int n, float* __restrict__ out) {
  float acc = 0.f;
  const int nv = n >> 2;  // n = 512 -> 128 float4
  const float4* __restrict__ p4 = reinterpret_cast<const float4*>(partial);
  for (int i = threadIdx.x; i < nv; i += 256) {
    const float4 v = p4[i];
    acc += (v.x + v.y) + (v.z + v.w);
  }
#pragma unroll
  for (int off = 32; off > 0; off >>= 1) acc += __shfl_down(acc, off, 64);
  __shared__ float wsum[4];
  if ((threadIdx.x & 63) == 0) wsum[threadIdx.x >> 6] = acc;
  __syncthreads();
  if (threadIdx.x == 0) {
    const float s = wsum[0] + wsum[1] + wsum[2] + wsum[3];
    out[0] = 1.f - s * (1.f / (float)(NPLANES * IMG_H * IMG_W));
  }
}

extern "C" void kernel_launch(void* const* d_in, const int* in_sizes, int n_in,
                              void* d_out, int out_size, void* d_ws, size_t ws_size,
                              hipStream_t stream) {
  const float* enhanced = (const float*)d_in[0];
  const float* target = (const float*)d_in[1];
  float* out = (float*)d_out;
  float* partial = (float*)d_ws;

  ssim_pipe_kernel<<<dim3(NBLOCKS, 1, 1), dim3(256, 1, 1), 0, stream>>>(
      enhanced, target, partial);
  ssim_reduce_kernel<<<1, 256, 0, stream>>>(partial, NBLOCKS, out);
}

// Round 5
// 162.319 us; speedup vs baseline: 1.3343x; 1.3300x over previous
//
#include <hip/hip_runtime.h>

// SSIM loss, fused. Input: enhanced, target fp32 [16,3,512,512]. Output: scalar fp32.
// V6 = V3 chassis + two cuts:
//  (a) 4 channels instead of 5: mu1, mu2, S=conv(x^2+y^2), XY=conv(x*y).
//      sigma1+sigma2 = S - (mu1^2+mu2^2)  -- exact algebra, conv is linear.
//  (b) channel-pair float2 LDS layout: v-pass = 20 ds_read_b64 (conflict-free)
//      instead of 50 ds_read_b32; h-pass = 8 ds_write_b64 (conflict-free).

#define TILE_W 64
#define TILE_H 16
#define HALO 3
#define IN_H 22                      // TILE_H + 2*HALO
#define H_PAIRS 66                   // float2 per row: 64 + 2 pad (row bank-rot 4)
#define IMG_H 512
#define IMG_W 512
#define NPLANES 48                   // 16 * 3
#define SSIM_C1 1.0e-4f
#define SSIM_C2 9.0e-4f

static __device__ constexpr float G[7] = {
    0.03663284536f, 0.11128076166f, 0.21674531251f, 0.27068216094f,
    0.21674531251f, 0.11128076166f, 0.03663284536f};

// Aligned float4 load with zero fill outside [0, IMG_W). col is a multiple of 4.
__device__ __forceinline__ float4 ld4z(const float* __restrict__ row, int col) {
  if (col >= 0 && col + 3 < IMG_W) {
    return *reinterpret_cast<const float4*>(row + col);
  }
  float4 v;
  v.x = ((unsigned)(col + 0) < IMG_W) ? row[col + 0] : 0.f;
  v.y = ((unsigned)(col + 1) < IMG_W) ? row[col + 1] : 0.f;
  v.z = ((unsigned)(col + 2) < IMG_W) ? row[col + 2] : 0.f;
  v.w = ((unsigned)(col + 3) < IMG_W) ? row[col + 3] : 0.f;
  return v;
}

__global__ __launch_bounds__(256, 6) void ssim_tile_kernel(
    const float* __restrict__ x, const float* __restrict__ y,
    float* __restrict__ partial) {
  // Pair-plane 0: (mu1, mu2); pair-plane 1: (S, XY). 23,232 B -> 6 blocks/CU.
  __shared__ __align__(16) float2 hbuf[2][IN_H][H_PAIRS];

  const int tid = threadIdx.x;
  const int plane = blockIdx.z;
  const float* __restrict__ xp = x + (size_t)plane * (IMG_H * IMG_W);
  const float* __restrict__ yp = y + (size_t)plane * (IMG_H * IMG_W);
  const int y0 = blockIdx.y * TILE_H - HALO;
  const int cbase = blockIdx.x * TILE_W - 4;  // window col 0 (output col - 4)
  const bool edge = (blockIdx.x == 0) | (blockIdx.x == gridDim.x - 1) |
                    (blockIdx.y == 0) | (blockIdx.y == gridDim.y - 1);

  // ---- Horizontal 7-tap pass: item = (row, 4 adjacent output cols). ----
  // 12-float window [cbase+4cg .. +11]; output j uses window indices j+1..j+7.
  for (int item = tid; item < IN_H * 16; item += 256) {
    const int hr = item >> 4;
    const int cg = item & 15;
    const int bcol = cbase + 4 * cg;
    float xin[12], yin[12];
    if (!edge) {
      const float* xr = xp + (size_t)(y0 + hr) * IMG_W + bcol;
      const float* yr = yp + (size_t)(y0 + hr) * IMG_W + bcol;
      const float4 xa = *reinterpret_cast<const float4*>(xr);
      const float4 xb = *reinterpret_cast<const float4*>(xr + 4);
      const float4 xc = *reinterpret_cast<const float4*>(xr + 8);
      const float4 ya = *reinterpret_cast<const float4*>(yr);
      const float4 yb = *reinterpret_cast<const float4*>(yr + 4);
      const float4 yc = *reinterpret_cast<const float4*>(yr + 8);
      xin[0] = xa.x; xin[1] = xa.y; xin[2] = xa.z; xin[3] = xa.w;
      xin[4] = xb.x; xin[5] = xb.y; xin[6] = xb.z; xin[7] = xb.w;
      xin[8] = xc.x; xin[9] = xc.y; xin[10] = xc.z; xin[11] = xc.w;
      yin[0] = ya.x; yin[1] = ya.y; yin[2] = ya.z; yin[3] = ya.w;
      yin[4] = yb.x; yin[5] = yb.y; yin[6] = yb.z; yin[7] = yb.w;
      yin[8] = yc.x; yin[9] = yc.y; yin[10] = yc.z; yin[11] = yc.w;
    } else {
      const int gy = y0 + hr;
      if ((unsigned)gy < IMG_H) {
        const float* xr = xp + (size_t)gy * IMG_W;
        const float* yr = yp + (size_t)gy * IMG_W;
#pragma unroll
        for (int v = 0; v < 3; ++v) {
          const float4 a = ld4z(xr, bcol + 4 * v);
          const float4 b = ld4z(yr, bcol + 4 * v);
          xin[4 * v + 0] = a.x; xin[4 * v + 1] = a.y;
          xin[4 * v + 2] = a.z; xin[4 * v + 3] = a.w;
          yin[4 * v + 0] = b.x; yin[4 * v + 1] = b.y;
          yin[4 * v + 2] = b.z; yin[4 * v + 3] = b.w;
        }
      } else {
#pragma unroll
        for (int i = 0; i < 12; ++i) { xin[i] = 0.f; yin[i] = 0.f; }
      }
    }
    // Products once per window column, scatter into the <=4 outputs using it.
    float a1[4] = {0.f, 0.f, 0.f, 0.f};
    float a2[4] = {0.f, 0.f, 0.f, 0.f};
    float aS[4] = {0.f, 0.f, 0.f, 0.f};
    float aXY[4] = {0.f, 0.f, 0.f, 0.f};
#pragma unroll
    for (int w = 1; w < 12; ++w) {
      const float xv = xin[w];
      const float yv = yin[w];
      const float ps = fmaf(xv, xv, yv * yv);  // x^2 + y^2
      const float pxy = xv * yv;
#pragma unroll
      for (int j = 0; j < 4; ++j) {
        const int k = w - 1 - j;  // tap index for output col j
        if (k >= 0 && k < 7) {
          const float gk = G[k];
          a1[j] = fmaf(gk, xv, a1[j]);
          a2[j] = fmaf(gk, yv, a2[j]);
          aS[j] = fmaf(gk, ps, aS[j]);
          aXY[j] = fmaf(gk, pxy, aXY[j]);
        }
      }
    }
    // Conflict-free b64 writes: word addr = 4*hr + 2*(4cg+j) (mod 32 spread).
    float2* b0 = &hbuf[0][hr][4 * cg];
    float2* b1 = &hbuf[1][hr][4 * cg];
#pragma unroll
    for (int j = 0; j < 4; ++j) {
      b0[j] = make_float2(a1[j], a2[j]);
      b1[j] = make_float2(aS[j], aXY[j]);
    }
  }
  __syncthreads();

  // ---- Vertical 7-tap pass + SSIM map. ----
  // Thread = (column c, 4 consecutive output rows r0..r0+3). Lane = c ->
  // b64 word addr (132*r + 2c): 128 words over 32 banks = 4/bank, conflict-free.
  const int c = tid & 63;
  const int r0 = (tid >> 6) * 4;  // wave w owns rows 4w..4w+3
  float m1[4] = {0.f, 0.f, 0.f, 0.f};
  float m2[4] = {0.f, 0.f, 0.f, 0.f};
  float eS[4] = {0.f, 0.f, 0.f, 0.f};
  float eXY[4] = {0.f, 0.f, 0.f, 0.f};
#pragma unroll
  for (int j = 0; j < 10; ++j) {  // input rows r0+j, immediate offsets
    const float2 mv = hbuf[0][r0 + j][c];
    const float2 sv = hbuf[1][r0 + j][c];
#pragma unroll
    for (int t = 0; t < 4; ++t) {
      const int k = j - t;  // tap index for output row r0+t
      if (k >= 0 && k < 7) {
        const float gk = G[k];
        m1[t] = fmaf(gk, mv.x, m1[t]);
        m2[t] = fmaf(gk, mv.y, m2[t]);
        eS[t] = fmaf(gk, sv.x, eS[t]);
        eXY[t] = fmaf(gk, sv.y, eXY[t]);
      }
    }
  }

  float acc = 0.f;
#pragma unroll
  for (int t = 0; t < 4; ++t) {
    const float mu12 = m1[t] * m2[t];
    const float msq = fmaf(m1[t], m1[t], m2[t] * m2[t]);  // mu1^2 + mu2^2
    const float sig12 = eXY[t] - mu12;
    const float sigsum = eS[t] - msq;                     // sigma1 + sigma2
    const float num = fmaf(2.f, mu12, SSIM_C1) * fmaf(2.f, sig12, SSIM_C2);
    const float den = (msq + SSIM_C1) * (sigsum + SSIM_C2);
    float r = __builtin_amdgcn_rcpf(den);  // den > 0 always
    r = r * fmaf(-den, r, 2.f);            // 1 Newton step, ~1 ulp
    acc = fmaf(num, r, acc);
  }

  // Block reduction: wave64 shuffle tree, then LDS across 4 waves.
#pragma unroll
  for (int off = 32; off > 0; off >>= 1) acc += __shfl_down(acc, off, 64);
  __shared__ float wsum[4];
  if ((tid & 63) == 0) wsum[tid >> 6] = acc;
  __syncthreads();
  if (tid == 0) {
    const float s = wsum[0] + wsum[1] + wsum[2] + wsum[3];
    partial[(size_t)blockIdx.z * gridDim.x * gridDim.y +
            (size_t)blockIdx.y * gridDim.x + blockIdx.x] = s;
  }
}

__global__ __launch_bounds__(256) void ssim_reduce_kernel(
    const float* __restrict__ partial, int n, float* __restrict__ out) {
  float acc = 0.f;
  const int nv = n >> 2;  // n = 12288 -> 3072 float4
  const float4* __restrict__ p4 = reinterpret_cast<const float4*>(partial);
  for (int i = threadIdx.x; i < nv; i += 256) {
    const float4 v = p4[i];
    acc += (v.x + v.y) + (v.z + v.w);
  }
#pragma unroll
  for (int off = 32; off > 0; off >>= 1) acc += __shfl_down(acc, off, 64);
  __shared__ float wsum[4];
  if ((threadIdx.x & 63) == 0) wsum[threadIdx.x >> 6] = acc;
  __syncthreads();
  if (threadIdx.x == 0) {
    const float s = wsum[0] + wsum[1] + wsum[2] + wsum[3];
    out[0] = 1.f - s * (1.f / (float)(NPLANES * IMG_H * IMG_W));
  }
}

extern "C" void kernel_launch(void* const* d_in, const int* in_sizes, int n_in,
                              void* d_out, int out_size, void* d_ws, size_t ws_size,
                              hipStream_t stream) {
  const float* enhanced = (const float*)d_in[0];
  const float* target = (const float*)d_in[1];
  float* out = (float*)d_out;
  float* partial = (float*)d_ws;

  dim3 grid(IMG_W / TILE_W, IMG_H / TILE_H, NPLANES);  // 8 x 32 x 48 = 12288
  dim3 block(256, 1, 1);
  ssim_tile_kernel<<<grid, block, 0, stream>>>(enhanced, target, partial);

  const int nblocks = (IMG_W / TILE_W) * (IMG_H / TILE_H) * NPLANES;
  ssim_reduce_kernel<<<1, 256, 0, stream>>>(partial, nblocks, out);
}

// Round 6
// 158.224 us; speedup vs baseline: 1.3688x; 1.0259x over previous
//
#include <hip/hip_runtime.h>

// SSIM loss, fused. Input: enhanced, target fp32 [16,3,512,512]. Output: scalar fp32.
// V7 = V6 chassis + packed-fp32 math + item8 h-pass:
//  - 4 channels as 2 float2 pairs: (mu1,mu2), (S=conv(x^2+y^2), XY=conv(x*y)).
//  - v_pk_fma_f32 (inline asm) does both channels of a pair per tap.
//  - h-pass item = (row, 8 cols): 176 items, 8 float4 loads (shared window),
//    all global loads issue in one batch at block start.
//  - LDS row pad 67 float2; conflict-free-ish b64 traffic.

#define TILE_W 64
#define TILE_H 16
#define HALO 3
#define IN_H 22                      // TILE_H + 2*HALO
#define H_PAIRS 67                   // float2 per row: 64 + 3 pad (write bank spread)
#define IMG_H 512
#define IMG_W 512
#define NPLANES 48                   // 16 * 3
#define SSIM_C1 1.0e-4f
#define SSIM_C2 9.0e-4f

static __device__ constexpr float G[7] = {
    0.03663284536f, 0.11128076166f, 0.21674531251f, 0.27068216094f,
    0.21674531251f, 0.11128076166f, 0.03663284536f};

// Packed fp32 FMA: d.lo = fma(a.lo,b.lo,c.lo), d.hi = fma(a.hi,b.hi,c.hi).
__device__ __forceinline__ float2 pk_fma(const float2 a, const float2 b,
                                         const float2 c) {
  float2 d;
  asm("v_pk_fma_f32 %0, %1, %2, %3" : "=v"(d) : "v"(a), "v"(b), "v"(c));
  return d;
}

// Aligned float4 load with zero fill outside [0, IMG_W). col is a multiple of 4.
__device__ __forceinline__ float4 ld4z(const float* __restrict__ row, int col) {
  if (col >= 0 && col + 3 < IMG_W) {
    return *reinterpret_cast<const float4*>(row + col);
  }
  float4 v;
  v.x = ((unsigned)(col + 0) < IMG_W) ? row[col + 0] : 0.f;
  v.y = ((unsigned)(col + 1) < IMG_W) ? row[col + 1] : 0.f;
  v.z = ((unsigned)(col + 2) < IMG_W) ? row[col + 2] : 0.f;
  v.w = ((unsigned)(col + 3) < IMG_W) ? row[col + 3] : 0.f;
  return v;
}

__global__ __launch_bounds__(256, 6) void ssim_tile_kernel(
    const float* __restrict__ x, const float* __restrict__ y,
    float* __restrict__ partial) {
  // Pair-plane 0: (mu1, mu2); pair-plane 1: (S, XY). 23,584 B -> 6 blocks/CU.
  __shared__ __align__(16) float2 hbuf[2][IN_H][H_PAIRS];

  const int tid = threadIdx.x;
  const int plane = blockIdx.z;
  const float* __restrict__ xp = x + (size_t)plane * (IMG_H * IMG_W);
  const float* __restrict__ yp = y + (size_t)plane * (IMG_H * IMG_W);
  const int y0 = blockIdx.y * TILE_H - HALO;
  const int x0 = blockIdx.x * TILE_W;
  const bool edge = (blockIdx.x == 0) | (blockIdx.x == gridDim.x - 1) |
                    (blockIdx.y == 0) | (blockIdx.y == gridDim.y - 1);

  // ---- Horizontal 7-tap pass: item8 = (row, 8 adjacent output cols). ----
  // 176 items; thread t < 176 owns item t. 16-float window [8cg-4, 8cg+11];
  // output j (0..7) uses window indices j+1..j+7.
  if (tid < IN_H * 8) {
    const int hr = tid >> 3;
    const int cg = tid & 7;
    const int bcol = x0 + 8 * cg - 4;  // aligned to 4
    float wx[16], wy[16];
    const int gy = y0 + hr;
    if (!edge) {
      const float* xr = xp + (size_t)gy * IMG_W + bcol;
      const float* yr = yp + (size_t)gy * IMG_W + bcol;
#pragma unroll
      for (int v = 0; v < 4; ++v) {
        const float4 a = *reinterpret_cast<const float4*>(xr + 4 * v);
        const float4 b = *reinterpret_cast<const float4*>(yr + 4 * v);
        wx[4 * v + 0] = a.x; wx[4 * v + 1] = a.y;
        wx[4 * v + 2] = a.z; wx[4 * v + 3] = a.w;
        wy[4 * v + 0] = b.x; wy[4 * v + 1] = b.y;
        wy[4 * v + 2] = b.z; wy[4 * v + 3] = b.w;
      }
    } else if ((unsigned)gy < IMG_H) {
      const float* xr = xp + (size_t)gy * IMG_W;
      const float* yr = yp + (size_t)gy * IMG_W;
#pragma unroll
      for (int v = 0; v < 4; ++v) {
        const float4 a = ld4z(xr, bcol + 4 * v);
        const float4 b = ld4z(yr, bcol + 4 * v);
        wx[4 * v + 0] = a.x; wx[4 * v + 1] = a.y;
        wx[4 * v + 2] = a.z; wx[4 * v + 3] = a.w;
        wy[4 * v + 0] = b.x; wy[4 * v + 1] = b.y;
        wy[4 * v + 2] = b.z; wy[4 * v + 3] = b.w;
      }
    } else {
#pragma unroll
      for (int i = 0; i < 16; ++i) { wx[i] = 0.f; wy[i] = 0.f; }
    }
    // Pair accumulators: A[j] = (mu1,mu2), B[j] = (S, XY).
    float2 A[8], B[8];
#pragma unroll
    for (int j = 0; j < 8; ++j) {
      A[j] = make_float2(0.f, 0.f);
      B[j] = make_float2(0.f, 0.f);
    }
#pragma unroll
    for (int wi = 1; wi < 15; ++wi) {
      const float xv = wx[wi];
      const float yv = wy[wi];
      const float2 xyp = make_float2(xv, yv);
      const float2 spp = make_float2(fmaf(xv, xv, yv * yv), xv * yv);
#pragma unroll
      for (int j = 0; j < 8; ++j) {
        const int k = wi - 1 - j;  // tap index for output col j
        if (k >= 0 && k < 7) {
          const float2 gk2 = make_float2(G[k], G[k]);
          A[j] = pk_fma(gk2, xyp, A[j]);
          B[j] = pk_fma(gk2, spp, B[j]);
        }
      }
    }
    float2* b0 = &hbuf[0][hr][8 * cg];
    float2* b1 = &hbuf[1][hr][8 * cg];
#pragma unroll
    for (int j = 0; j < 8; ++j) {
      b0[j] = A[j];
      b1[j] = B[j];
    }
  }
  __syncthreads();

  // ---- Vertical 7-tap pass + SSIM map. ----
  // Thread = (column c, 4 consecutive output rows). Lane = c -> contiguous
  // b64 reads (128 words/32 banks = uniform), conflict-free.
  const int c = tid & 63;
  const int r0 = (tid >> 6) * 4;  // wave w owns rows 4w..4w+3
  float2 M[4], S4[4];
#pragma unroll
  for (int t = 0; t < 4; ++t) {
    M[t] = make_float2(0.f, 0.f);
    S4[t] = make_float2(0.f, 0.f);
  }
#pragma unroll
  for (int j = 0; j < 10; ++j) {  // input rows r0+j, immediate offsets
    const float2 mv = hbuf[0][r0 + j][c];
    const float2 sv = hbuf[1][r0 + j][c];
#pragma unroll
    for (int t = 0; t < 4; ++t) {
      const int k = j - t;  // tap index for output row r0+t
      if (k >= 0 && k < 7) {
        const float2 gk2 = make_float2(G[k], G[k]);
        M[t] = pk_fma(gk2, mv, M[t]);
        S4[t] = pk_fma(gk2, sv, S4[t]);
      }
    }
  }

  float acc = 0.f;
#pragma unroll
  for (int t = 0; t < 4; ++t) {
    const float mu1 = M[t].x, mu2 = M[t].y;
    const float eS = S4[t].x, eXY = S4[t].y;
    const float mu12 = mu1 * mu2;
    const float msq = fmaf(mu1, mu1, mu2 * mu2);  // mu1^2 + mu2^2
    const float sig12 = eXY - mu12;
    const float sigsum = eS - msq;                // sigma1 + sigma2
    const float num = fmaf(2.f, mu12, SSIM_C1) * fmaf(2.f, sig12, SSIM_C2);
    const float den = (msq + SSIM_C1) * (sigsum + SSIM_C2);
    float r = __builtin_amdgcn_rcpf(den);  // den > 0 always
    r = r * fmaf(-den, r, 2.f);            // 1 Newton step, ~1 ulp
    acc = fmaf(num, r, acc);
  }

  // Block reduction: wave64 shuffle tree, then LDS across 4 waves.
#pragma unroll
  for (int off = 32; off > 0; off >>= 1) acc += __shfl_down(acc, off, 64);
  __shared__ float wsum[4];
  if ((tid & 63) == 0) wsum[tid >> 6] = acc;
  __syncthreads();
  if (tid == 0) {
    const float s = wsum[0] + wsum[1] + wsum[2] + wsum[3];
    partial[(size_t)blockIdx.z * gridDim.x * gridDim.y +
            (size_t)blockIdx.y * gridDim.x + blockIdx.x] = s;
  }
}

__global__ __launch_bounds__(1024) void ssim_reduce_kernel(
    const float* __restrict__ partial, int n, float* __restrict__ out) {
  float acc = 0.f;
  const int nv = n >> 2;  // n = 12288 -> 3072 float4
  const float4* __restrict__ p4 = reinterpret_cast<const float4*>(partial);
  for (int i = threadIdx.x; i < nv; i += 1024) {
    const float4 v = p4[i];
    acc += (v.x + v.y) + (v.z + v.w);
  }
#pragma unroll
  for (int off = 32; off > 0; off >>= 1) acc += __shfl_down(acc, off, 64);
  __shared__ float wsum[16];
  if ((threadIdx.x & 63) == 0) wsum[threadIdx.x >> 6] = acc;
  __syncthreads();
  if (threadIdx.x == 0) {
    float s = 0.f;
#pragma unroll
    for (int w = 0; w < 16; ++w) s += wsum[w];
    out[0] = 1.f - s * (1.f / (float)(NPLANES * IMG_H * IMG_W));
  }
}

extern "C" void kernel_launch(void* const* d_in, const int* in_sizes, int n_in,
                              void* d_out, int out_size, void* d_ws, size_t ws_size,
                              hipStream_t stream) {
  const float* enhanced = (const float*)d_in[0];
  const float* target = (const float*)d_in[1];
  float* out = (float*)d_out;
  float* partial = (float*)d_ws;

  dim3 grid(IMG_W / TILE_W, IMG_H / TILE_H, NPLANES);  // 8 x 32 x 48 = 12288
  dim3 block(256, 1, 1);
  ssim_tile_kernel<<<grid, block, 0, stream>>>(enhanced, target, partial);

  const int nblocks = (IMG_W / TILE_W) * (IMG_H / TILE_H) * NPLANES;
  ssim_reduce_kernel<<<1, 1024, 0, stream>>>(partial, nblocks, out);
}

// Round 7
// 145.505 us; speedup vs baseline: 1.4885x; 1.0874x over previous
//
#include <hip/hip_runtime.h>

// SSIM loss, fused. Input: enhanced, target fp32 [16,3,512,512]. Output: scalar fp32.
// V8 = V7 math (4 channels, pk_fma, item8) + row-chain blocks:
//  - 1 block = one (ty, plane) row of 8 x-tiles; grid 1536 (8x fewer dispatches,
//    prologue latency amortized 8x, halo columns L1-hot across tiles).
//  - double-buffered LDS (46.5 KB -> 3 blocks/CU), register prefetch of next
//    tile (32 floats), lgkmcnt-only barrier (prefetch stays in flight), one
//    barrier per tile.
//  - h-pass writes are ds_write_b128 with H_PAIRS=66: start banks
//    {4hr+16cg}%32 span 4 words -> all 32 banks tiled per half-wave window;
//    v-pass b64 reads uniform (132%32=4). Conflict-free both sides.

#define TILE_W 64
#define TILE_H 16
#define HALO 3
#define IN_H 22                      // TILE_H + 2*HALO
#define H_PAIRS 66                   // float2 per row (132 words; 132%32=4)
#define IMG_H 512
#define IMG_W 512
#define NPLANES 48                   // 16 * 3
#define NTX 8                        // x-tiles per row chain
#define SSIM_C1 1.0e-4f
#define SSIM_C2 9.0e-4f

static __device__ constexpr float G[7] = {
    0.03663284536f, 0.11128076166f, 0.21674531251f, 0.27068216094f,
    0.21674531251f, 0.11128076166f, 0.03663284536f};

// Packed fp32 FMA: d.lo = fma(a.lo,b.lo,c.lo), d.hi = fma(a.hi,b.hi,c.hi).
__device__ __forceinline__ float2 pk_fma(const float2 a, const float2 b,
                                         const float2 c) {
  float2 d;
  asm("v_pk_fma_f32 %0, %1, %2, %3" : "=v"(d) : "v"(a), "v"(b), "v"(c));
  return d;
}

// Aligned float4 load with zero fill outside [0, IMG_W). col is a multiple of 4.
__device__ __forceinline__ float4 ld4z(const float* __restrict__ row, int col) {
  if (col >= 0 && col + 3 < IMG_W) {
    return *reinterpret_cast<const float4*>(row + col);
  }
  float4 v;
  v.x = ((unsigned)(col + 0) < IMG_W) ? row[col + 0] : 0.f;
  v.y = ((unsigned)(col + 1) < IMG_W) ? row[col + 1] : 0.f;
  v.z = ((unsigned)(col + 2) < IMG_W) ? row[col + 2] : 0.f;
  v.w = ((unsigned)(col + 3) < IMG_W) ? row[col + 3] : 0.f;
  return v;
}

// Barrier that keeps prefetch global loads in flight: wait LDS ops only.
__device__ __forceinline__ void lds_barrier() {
  __builtin_amdgcn_sched_barrier(0);
  asm volatile("s_waitcnt lgkmcnt(0)" ::: "memory");
  __builtin_amdgcn_s_barrier();
  __builtin_amdgcn_sched_barrier(0);
}

__global__ __launch_bounds__(256, 3) void ssim_row_kernel(
    const float* __restrict__ x, const float* __restrict__ y,
    float* __restrict__ partial) {
  // [buf][pair-plane][row][col]; plane 0: (mu1,mu2), plane 1: (S, XY).
  __shared__ __align__(16) float2 hbuf[2][2][IN_H][H_PAIRS];  // 46,464 B

  const int tid = threadIdx.x;
  const int ty = blockIdx.x;           // 32 tile-rows
  const int plane = blockIdx.y;        // 48 planes
  const float* __restrict__ xp = x + (size_t)plane * (IMG_H * IMG_W);
  const float* __restrict__ yp = y + (size_t)plane * (IMG_H * IMG_W);
  const int y0 = ty * TILE_H - HALO;
  const bool edge_y = (ty == 0) | (ty == 31);

  // h-pass item8: thread t<176 owns (row t>>3, 8-col group t&7).
  const int hr = tid >> 3;
  const int cg = tid & 7;
  const bool active = tid < IN_H * 8;  // 176
  const int gy = y0 + hr;

  float4 px[4], py[4];  // prefetched 16-float window per image

  // Issue global loads for tile tx into px/py.
  auto load_tile = [&](int tx) {
    const int bcol = tx * TILE_W + 8 * cg - 4;
    const bool edge = edge_y | (tx == 0) | (tx == NTX - 1);
    if (!edge) {
      const float* xr = xp + (size_t)gy * IMG_W + bcol;
      const float* yr = yp + (size_t)gy * IMG_W + bcol;
#pragma unroll
      for (int v = 0; v < 4; ++v) {
        px[v] = *reinterpret_cast<const float4*>(xr + 4 * v);
        py[v] = *reinterpret_cast<const float4*>(yr + 4 * v);
      }
    } else if ((unsigned)gy < IMG_H) {
      const float* xr = xp + (size_t)gy * IMG_W;
      const float* yr = yp + (size_t)gy * IMG_W;
#pragma unroll
      for (int v = 0; v < 4; ++v) {
        px[v] = ld4z(xr, bcol + 4 * v);
        py[v] = ld4z(yr, bcol + 4 * v);
      }
    } else {
      const float4 z = make_float4(0.f, 0.f, 0.f, 0.f);
#pragma unroll
      for (int v = 0; v < 4; ++v) { px[v] = z; py[v] = z; }
    }
  };

  // Horizontal 7-tap over the prefetched window; b128 writes into buffer b.
  auto h_pass = [&](int b) {
    const float wx[16] = {px[0].x, px[0].y, px[0].z, px[0].w,
                          px[1].x, px[1].y, px[1].z, px[1].w,
                          px[2].x, px[2].y, px[2].z, px[2].w,
                          px[3].x, px[3].y, px[3].z, px[3].w};
    const float wy[16] = {py[0].x, py[0].y, py[0].z, py[0].w,
                          py[1].x, py[1].y, py[1].z, py[1].w,
                          py[2].x, py[2].y, py[2].z, py[2].w,
                          py[3].x, py[3].y, py[3].z, py[3].w};
    float2 A[8], B[8];
#pragma unroll
    for (int j = 0; j < 8; ++j) {
      A[j] = make_float2(0.f, 0.f);
      B[j] = make_float2(0.f, 0.f);
    }
#pragma unroll
    for (int wi = 1; wi < 15; ++wi) {
      const float xv = wx[wi];
      const float yv = wy[wi];
      const float2 xyp = make_float2(xv, yv);
      const float2 spp = make_float2(fmaf(xv, xv, yv * yv), xv * yv);
#pragma unroll
      for (int j = 0; j < 8; ++j) {
        const int k = wi - 1 - j;  // tap index for output col j
        if (k >= 0 && k < 7) {
          const float2 gk2 = make_float2(G[k], G[k]);
          A[j] = pk_fma(gk2, xyp, A[j]);
          B[j] = pk_fma(gk2, spp, B[j]);
        }
      }
    }
    float4* w0 = reinterpret_cast<float4*>(&hbuf[b][0][hr][8 * cg]);
    float4* w1 = reinterpret_cast<float4*>(&hbuf[b][1][hr][8 * cg]);
#pragma unroll
    for (int q = 0; q < 4; ++q) {
      w0[q] = make_float4(A[2 * q].x, A[2 * q].y, A[2 * q + 1].x, A[2 * q + 1].y);
      w1[q] = make_float4(B[2 * q].x, B[2 * q].y, B[2 * q + 1].x, B[2 * q + 1].y);
    }
  };

  // Vertical 7-tap + SSIM map over buffer b; thread = (col tid&63, 4 rows).
  const int c = tid & 63;
  const int r0 = (tid >> 6) * 4;
  auto v_pass = [&](int b) -> float {
    float2 M[4], S4[4];
#pragma unroll
    for (int t = 0; t < 4; ++t) {
      M[t] = make_float2(0.f, 0.f);
      S4[t] = make_float2(0.f, 0.f);
    }
#pragma unroll
    for (int j = 0; j < 10; ++j) {
      const float2 mv = hbuf[b][0][r0 + j][c];
      const float2 sv = hbuf[b][1][r0 + j][c];
#pragma unroll
      for (int t = 0; t < 4; ++t) {
        const int k = j - t;  // tap index for output row r0+t
        if (k >= 0 && k < 7) {
          const float2 gk2 = make_float2(G[k], G[k]);
          M[t] = pk_fma(gk2, mv, M[t]);
          S4[t] = pk_fma(gk2, sv, S4[t]);
        }
      }
    }
    float a = 0.f;
#pragma unroll
    for (int t = 0; t < 4; ++t) {
      const float mu1 = M[t].x, mu2 = M[t].y;
      const float mu12 = mu1 * mu2;
      const float msq = fmaf(mu1, mu1, mu2 * mu2);  // mu1^2 + mu2^2
      const float sig12 = S4[t].y - mu12;
      const float sigsum = S4[t].x - msq;           // sigma1 + sigma2
      const float num = fmaf(2.f, mu12, SSIM_C1) * fmaf(2.f, sig12, SSIM_C2);
      const float den = (msq + SSIM_C1) * (sigsum + SSIM_C2);
      float r = __builtin_amdgcn_rcpf(den);  // den > 0 always
      r = r * fmaf(-den, r, 2.f);            // 1 Newton step, ~1 ulp
      a = fmaf(num, r, a);
    }
    return a;
  };

  float acc = 0.f;
  if (active) load_tile(0);
#pragma unroll 2
  for (int q = 0; q < NTX; ++q) {
    const int b = q & 1;
    if (active) {
      h_pass(b);                      // consumes prefetch (vmcnt by compiler)
      if (q < NTX - 1) load_tile(q + 1);  // issue next tile's loads
    }
    lds_barrier();                    // LDS visible; global loads stay in flight
    acc += v_pass(b);
    // No second barrier needed: a wave writing buf b at tile q+2 has passed
    // barrier q+1, which every wave reaches only after v_pass(b) at tile q.
  }

  // Block reduction once per row-chain (8 tiles accumulated per thread).
#pragma unroll
  for (int off = 32; off > 0; off >>= 1) acc += __shfl_down(acc, off, 64);
  __shared__ float wsum[4];
  if ((tid & 63) == 0) wsum[tid >> 6] = acc;
  __syncthreads();
  if (tid == 0) {
    partial[(size_t)plane * 32 + ty] = wsum[0] + wsum[1] + wsum[2] + wsum[3];
  }
}

__global__ __launch_bounds__(1024) void ssim_reduce_kernel(
    const float* __restrict__ partial, int n, float* __restrict__ out) {
  float acc = 0.f;
  const int nv = n >> 2;  // n = 1536 -> 384 float4
  const float4* __restrict__ p4 = reinterpret_cast<const float4*>(partial);
  for (int i = threadIdx.x; i < nv; i += 1024) {
    const float4 v = p4[i];
    acc += (v.x + v.y) + (v.z + v.w);
  }
#pragma unroll
  for (int off = 32; off > 0; off >>= 1) acc += __shfl_down(acc, off, 64);
  __shared__ float wsum[16];
  if ((threadIdx.x & 63) == 0) wsum[threadIdx.x >> 6] = acc;
  __syncthreads();
  if (threadIdx.x == 0) {
    float s = 0.f;
#pragma unroll
    for (int w = 0; w < 16; ++w) s += wsum[w];
    out[0] = 1.f - s * (1.f / (float)(NPLANES * IMG_H * IMG_W));
  }
}

extern "C" void kernel_launch(void* const* d_in, const int* in_sizes, int n_in,
                              void* d_out, int out_size, void* d_ws, size_t ws_size,
                              hipStream_t stream) {
  const float* enhanced = (const float*)d_in[0];
  const float* target = (const float*)d_in[1];
  float* out = (float*)d_out;
  float* partial = (float*)d_ws;

  dim3 grid(IMG_H / TILE_H, NPLANES, 1);  // 32 x 48 = 1536 row-chain blocks
  dim3 block(256, 1, 1);
  ssim_row_kernel<<<grid, block, 0, stream>>>(enhanced, target, partial);

  const int nblocks = (IMG_H / TILE_H) * NPLANES;  // 1536
  ssim_reduce_kernel<<<1, 1024, 0, stream>>>(partial, nblocks, out);
}